// Round 1
// baseline (1496.461 us; speedup 1.0000x reference)
//
#include <hip/hip_runtime.h>

#define NXD 128
#define NYD 128
#define SRC_XD 64
#define SRC_YD 64
#define T_STEPSD 256
#define BATCHD 8
#define N_PROBESD 4

// DPP cross-lane single shifts across the full wave64.
// Per LLVM AMDGPUAtomicOptimizer: ROW/WAVE_SHR delivers data from LOWER lane
// index (lane i <- lane i-1), SHL from HIGHER (lane i <- lane i+1).
// bound_ctrl=true zero-fills the invalid boundary lane -> matches the
// conv 'SAME' zero padding at col -1 / col 128.
__device__ __forceinline__ float dpp_from_lower(float v) { // lane i <- lane i-1, lane0 -> 0
    return __int_as_float(__builtin_amdgcn_update_dpp(0, __float_as_int(v), 0x138, 0xF, 0xF, true)); // WAVE_SHR1
}
__device__ __forceinline__ float dpp_from_upper(float v) { // lane i <- lane i+1, lane63 -> 0
    return __int_as_float(__builtin_amdgcn_update_dpp(0, __float_as_int(v), 0x130, 0xF, 0xF, true)); // WAVE_SHL1
}

// One workgroup per batch. 16 waves; wave w owns rows 8w..8w+7; lane l owns
// cols 2l,2l+1. Fields y1,y2 live entirely in registers (float2 per row).
// LDS only for: wave-boundary row halos (double-buffered), and the x series.
__global__ __launch_bounds__(1024) void wave_sim(
        const float* __restrict__ x,        // (T,B)
        const float* __restrict__ c,        // (NX,NY)
        const int*   __restrict__ probes,   // (4,2) int
        float* __restrict__ partial)        // (B,4) sums of v^2 over t
{
    __shared__ float haloTop[2][16][NYD];   // row 8w of wave w (top of band)
    __shared__ float haloBot[2][16][NYD];   // row 8w+7 of wave w (bottom of band)
    __shared__ float xs[T_STEPSD];

    const int tid = threadIdx.x;
    const int w = tid >> 6;       // wave id 0..15
    const int l = tid & 63;       // lane id
    const int b = blockIdx.x;     // batch

    // constants (match reference fp32 arithmetic)
    const float dt = 0.5f, bd = 0.005f;
    const float denom = 1.0f / (dt * dt) + 0.5f * bd / dt;   // 4.005
    const float inv_denom = 1.0f / denom;
    const float C2 = 2.0f * inv_denom;                        // constant forcing
    const float K2 = (-1.0f - dt * bd) * inv_denom;           // y2 coefficient
    const float KL = dt * dt * inv_denom;                     // laplacian coef scale

    // zero both halo buffers (initial y1 = 0)
    for (int i = tid; i < 2 * 16 * NYD; i += 1024) {
        ((float*)haloTop)[i] = 0.0f;
        ((float*)haloBot)[i] = 0.0f;
    }
    if (tid < T_STEPSD) xs[tid] = x[tid * BATCHD + b];

    // register state
    float2 A[8], B[8], coef[8];
#pragma unroll
    for (int r = 0; r < 8; ++r) {
        A[r] = make_float2(0.0f, 0.0f);
        B[r] = make_float2(0.0f, 0.0f);
        const float2 cc = ((const float2*)c)[((w * 8 + r) * NYD + 2 * l) >> 1];
        coef[r] = make_float2(KL * cc.x * cc.x, KL * cc.y * cc.y);
    }

    // probe ownership (exactly one thread per probe)
    bool own[N_PROBESD];
    int pro[N_PROBESD], pel[N_PROBESD];
    float acc[N_PROBESD];
#pragma unroll
    for (int j = 0; j < N_PROBESD; ++j) {
        const int px = probes[2 * j] & 127;
        const int py = probes[2 * j + 1] & 127;
        own[j] = ((px >> 3) == w) && ((py >> 1) == l);
        pro[j] = px & 7;
        pel[j] = py & 1;
        acc[j] = 0.0f;
    }
    const bool own_src = (((SRC_XD >> 3) == w) && ((SRC_YD >> 1) == l));

    __syncthreads();

    // One step: Y1 = current field, Y2 = previous field. Result is written
    // IN PLACE into Y2 (only read pointwise), so after the call Y2 holds the
    // new field -> caller alternates (A,B),(B,A) to avoid register moves.
    auto do_step = [&](float2 (&Y1)[8], float2 (&Y2)[8], int t) {
        const int buf = t & 1, nb = buf ^ 1;
        // halo rows from neighbor waves (zero beyond the grid)
        const int wa = (w == 0) ? 0 : w - 1;
        const int wb = (w == 15) ? 15 : w + 1;
        float2 ra = *(const float2*)&haloBot[buf][wa][2 * l];   // row 8w-1
        float2 rb = *(const float2*)&haloTop[buf][wb][2 * l];   // row 8w+8
        if (w == 0)  ra = make_float2(0.0f, 0.0f);
        if (w == 15) rb = make_float2(0.0f, 0.0f);
        const float xt = xs[t];

#pragma unroll
        for (int r = 0; r < 8; ++r) {
            const float2 up = (r == 0) ? ra : Y1[r - 1];
            const float2 dn = (r == 7) ? rb : Y1[r + 1];
            const float left0  = dpp_from_lower(Y1[r].y);  // col 2l-1 (lane l-1's c1)
            const float right1 = dpp_from_upper(Y1[r].x);  // col 2l+2 (lane l+1's c0)
            const float lapx = up.x + dn.x + left0    + Y1[r].y - 4.0f * Y1[r].x;
            const float lapy = up.y + dn.y + Y1[r].x  + right1  - 4.0f * Y1[r].y;
            const float nx = coef[r].x * lapx + C2 + K2 * Y2[r].x;
            const float ny = coef[r].y * lapy + C2 + K2 * Y2[r].y;
            Y2[r] = make_float2(nx, ny);
        }

        // source injection AFTER the division, matching reference .at[].add
        if (own_src) {
            if ((SRC_YD & 1) == 0) Y2[SRC_XD & 7].x += xt;
            else                   Y2[SRC_XD & 7].y += xt;
        }

        // probe accumulation (reads post-source field)
#pragma unroll
        for (int j = 0; j < N_PROBESD; ++j) {
            if (own[j]) {
                const int ro = pro[j];
                const float2 pv = (ro < 4)
                    ? ((ro < 2) ? ((ro == 0) ? Y2[0] : Y2[1]) : ((ro == 2) ? Y2[2] : Y2[3]))
                    : ((ro < 6) ? ((ro == 4) ? Y2[4] : Y2[5]) : ((ro == 6) ? Y2[6] : Y2[7]));
                const float v = pel[j] ? pv.y : pv.x;
                acc[j] += v * v;
            }
        }

        // publish new band-boundary rows (post-source: source row 64 IS a
        // band-top row, wave 8) into the other halo buffer
        *(float2*)&haloTop[nb][w][2 * l] = Y2[0];
        *(float2*)&haloBot[nb][w][2 * l] = Y2[7];
        __syncthreads();
    };

    for (int t = 0; t < T_STEPSD; t += 2) {
        do_step(A, B, t);       // new field in B
        do_step(B, A, t + 1);   // new field in A
    }

#pragma unroll
    for (int j = 0; j < N_PROBESD; ++j)
        if (own[j]) partial[b * N_PROBESD + j] = acc[j];
}

__global__ void reduce_k(const float* __restrict__ partial, float* __restrict__ out) {
    const int p = threadIdx.x;
    if (p < N_PROBESD) {
        float s = 0.0f, tot = 0.0f;
        for (int bb = 0; bb < BATCHD; ++bb) s += partial[bb * N_PROBESD + p];
        for (int i = 0; i < BATCHD * N_PROBESD; ++i) tot += partial[i];
        out[p] = s / tot;
    }
}

extern "C" void kernel_launch(void* const* d_in, const int* in_sizes, int n_in,
                              void* d_out, int out_size, void* d_ws, size_t ws_size,
                              hipStream_t stream) {
    const float* x      = (const float*)d_in[0];   // (256,8) f32
    const float* c      = (const float*)d_in[1];   // (128,128) f32
    const int*   probes = (const int*)d_in[2];     // (4,2) int
    float* out = (float*)d_out;                    // (4,) f32
    float* partial = (float*)d_ws;                 // (8,4) f32 scratch

    wave_sim<<<BATCHD, 1024, 0, stream>>>(x, c, probes, partial);
    reduce_k<<<1, 64, 0, stream>>>(partial, out);
}

// Round 2
// 270.862 us; speedup vs baseline: 5.5248x; 5.5248x over previous
//
#include <hip/hip_runtime.h>

#define NXD 128
#define NYD 128
#define SRC_XD 64
#define SRC_YD 64
#define T_STEPSD 256
#define BATCHD 8
#define N_PROBESD 4

// DPP cross-lane single shifts across the full wave64.
// WAVE_SHR1 (0x138): lane i <- lane i-1, lane0 -> 0 (bound_ctrl)
// WAVE_SHL1 (0x130): lane i <- lane i+1, lane63 -> 0
// Zero-fill matches the conv 'SAME' zero padding at col -1 / col 128.
__device__ __forceinline__ float dpp_from_lower(float v) {
    return __int_as_float(__builtin_amdgcn_update_dpp(0, __float_as_int(v), 0x138, 0xF, 0xF, true));
}
__device__ __forceinline__ float dpp_from_upper(float v) {
    return __int_as_float(__builtin_amdgcn_update_dpp(0, __float_as_int(v), 0x130, 0xF, 0xF, true));
}

#define ROW(up, dn, Yr, Zr, Kr) { \
    const float lf = dpp_from_lower((Yr).y); \
    const float rt = dpp_from_upper((Yr).x); \
    const float lapx = (up).x + (dn).x + lf + (Yr).y - 4.0f * (Yr).x; \
    const float lapy = (up).y + (dn).y + (Yr).x + rt - 4.0f * (Yr).y; \
    (Zr).x = (Kr).x * lapx + C2 + K2 * (Zr).x; \
    (Zr).y = (Kr).y * lapy + C2 + K2 * (Zr).y; \
}

#define PR1(ownj, proj, pelj, accj, Z0,Z1,Z2,Z3,Z4,Z5,Z6,Z7) \
    if (ownj) { \
        float2 pv = Z0; \
        if (proj == 1) pv = Z1; \
        if (proj == 2) pv = Z2; \
        if (proj == 3) pv = Z3; \
        if (proj == 4) pv = Z4; \
        if (proj == 5) pv = Z5; \
        if (proj == 6) pv = Z6; \
        if (proj == 7) pv = Z7; \
        const float v = (pelj) ? pv.y : pv.x; \
        accj += v * v; \
    }

#define STEP(Y0,Y1,Y2,Y3,Y4,Y5,Y6,Y7, Z0,Z1,Z2,Z3,Z4,Z5,Z6,Z7, tt) { \
    const int buf_ = (tt) & 1, nb_ = buf_ ^ 1; \
    float2 ra = *(const float2*)&haloBot[buf_][wa][2 * l]; \
    float2 rb = *(const float2*)&haloTop[buf_][wb][2 * l]; \
    if (w == 0)  ra = make_float2(0.0f, 0.0f); \
    if (w == 15) rb = make_float2(0.0f, 0.0f); \
    const float xt = xs[tt]; \
    ROW(ra, Y1, Y0, Z0, k0) \
    ROW(Y0, Y2, Y1, Z1, k1) \
    ROW(Y1, Y3, Y2, Z2, k2) \
    ROW(Y2, Y4, Y3, Z3, k3) \
    ROW(Y3, Y5, Y4, Z4, k4) \
    ROW(Y4, Y6, Y5, Z5, k5) \
    ROW(Y5, Y7, Y6, Z6, k6) \
    ROW(Y6, rb, Y7, Z7, k7) \
    if (own_src) Z0.x += xt; \
    PR1(own0, pro0, pel0, acc0, Z0,Z1,Z2,Z3,Z4,Z5,Z6,Z7) \
    PR1(own1, pro1, pel1, acc1, Z0,Z1,Z2,Z3,Z4,Z5,Z6,Z7) \
    PR1(own2, pro2, pel2, acc2, Z0,Z1,Z2,Z3,Z4,Z5,Z6,Z7) \
    PR1(own3, pro3, pel3, acc3, Z0,Z1,Z2,Z3,Z4,Z5,Z6,Z7) \
    *(float2*)&haloTop[nb_][w][2 * l] = Z0; \
    *(float2*)&haloBot[nb_][w][2 * l] = Z7; \
    __syncthreads(); \
}

__global__ __launch_bounds__(1024) void wave_sim(
        const float* __restrict__ x,
        const float* __restrict__ c,
        const int*   __restrict__ probes,
        float* __restrict__ partial)
{
    __shared__ float haloTop[2][16][NYD];
    __shared__ float haloBot[2][16][NYD];
    __shared__ float xs[T_STEPSD];

    const int tid = threadIdx.x;
    const int w = tid >> 6;
    const int l = tid & 63;
    const int b = blockIdx.x;

    const float dt = 0.5f, bdamp = 0.005f;
    const float denom = 1.0f / (dt * dt) + 0.5f * bdamp / dt;  // 4.005
    const float inv_denom = 1.0f / denom;
    const float C2 = 2.0f * inv_denom;
    const float K2 = (-1.0f - dt * bdamp) * inv_denom;
    const float KL = dt * dt * inv_denom;

    for (int i = tid; i < 2 * 16 * NYD; i += 1024) {
        ((float*)haloTop)[i] = 0.0f;
        ((float*)haloBot)[i] = 0.0f;
    }
    if (tid < T_STEPSD) xs[tid] = x[tid * BATCHD + b];

    const int rowbase = w * 8;
    const int colb = 2 * l;
#define LOADK(r) \
    float2 k##r; { \
        const float2 cc = *(const float2*)&c[(rowbase + r) * NYD + colb]; \
        k##r = make_float2(KL * cc.x * cc.x, KL * cc.y * cc.y); \
    }
    LOADK(0) LOADK(1) LOADK(2) LOADK(3) LOADK(4) LOADK(5) LOADK(6) LOADK(7)
#undef LOADK

    float2 a0 = make_float2(0.f,0.f), a1 = a0, a2 = a0, a3 = a0,
           a4 = a0, a5 = a0, a6 = a0, a7 = a0;
    float2 b0 = a0, b1 = a0, b2 = a0, b3 = a0, b4 = a0, b5 = a0, b6 = a0, b7 = a0;

    const int px0 = probes[0] & 127, py0 = probes[1] & 127;
    const int px1 = probes[2] & 127, py1 = probes[3] & 127;
    const int px2 = probes[4] & 127, py2 = probes[5] & 127;
    const int px3 = probes[6] & 127, py3 = probes[7] & 127;
    const bool own0 = ((px0 >> 3) == w) && ((py0 >> 1) == l);
    const bool own1 = ((px1 >> 3) == w) && ((py1 >> 1) == l);
    const bool own2 = ((px2 >> 3) == w) && ((py2 >> 1) == l);
    const bool own3 = ((px3 >> 3) == w) && ((py3 >> 1) == l);
    const int pro0 = px0 & 7, pel0 = py0 & 1;
    const int pro1 = px1 & 7, pel1 = py1 & 1;
    const int pro2 = px2 & 7, pel2 = py2 & 1;
    const int pro3 = px3 & 7, pel3 = py3 & 1;
    float acc0 = 0.f, acc1 = 0.f, acc2 = 0.f, acc3 = 0.f;
    const bool own_src = (((SRC_XD >> 3) == w) && ((SRC_YD >> 1) == l));

    const int wa = (w == 0) ? 0 : w - 1;
    const int wb = (w == 15) ? 15 : w + 1;

    __syncthreads();

    for (int t = 0; t < T_STEPSD; t += 2) {
        STEP(a0,a1,a2,a3,a4,a5,a6,a7, b0,b1,b2,b3,b4,b5,b6,b7, t)
        STEP(b0,b1,b2,b3,b4,b5,b6,b7, a0,a1,a2,a3,a4,a5,a6,a7, t + 1)
    }

    if (own0) partial[b * N_PROBESD + 0] = acc0;
    if (own1) partial[b * N_PROBESD + 1] = acc1;
    if (own2) partial[b * N_PROBESD + 2] = acc2;
    if (own3) partial[b * N_PROBESD + 3] = acc3;
}

__global__ void reduce_k(const float* __restrict__ partial, float* __restrict__ out) {
    const int p = threadIdx.x;
    if (p < N_PROBESD) {
        float s = 0.0f, tot = 0.0f;
        for (int bb = 0; bb < BATCHD; ++bb) s += partial[bb * N_PROBESD + p];
        for (int i = 0; i < BATCHD * N_PROBESD; ++i) tot += partial[i];
        out[p] = s / tot;
    }
}

extern "C" void kernel_launch(void* const* d_in, const int* in_sizes, int n_in,
                              void* d_out, int out_size, void* d_ws, size_t ws_size,
                              hipStream_t stream) {
    const float* x      = (const float*)d_in[0];
    const float* c      = (const float*)d_in[1];
    const int*   probes = (const int*)d_in[2];
    float* out = (float*)d_out;
    float* partial = (float*)d_ws;

    wave_sim<<<BATCHD, 1024, 0, stream>>>(x, c, probes, partial);
    reduce_k<<<1, 64, 0, stream>>>(partial, out);
}

// Round 3
// 235.526 us; speedup vs baseline: 6.3537x; 1.1500x over previous
//
#include <hip/hip_runtime.h>

#define NXD 128
#define NYD 128
#define SRC_XD 64
#define SRC_YD 64
#define T_STEPSD 256
#define BATCHD 8
#define N_PROBESD 4

typedef float v2f __attribute__((ext_vector_type(2)));

// DPP cross-lane single shifts across the full wave64.
// WAVE_SHR1 (0x138): lane i <- lane i-1, lane0 -> 0 (bound_ctrl)
// WAVE_SHL1 (0x130): lane i <- lane i+1, lane63 -> 0
// Zero-fill matches the conv 'SAME' zero padding at col -1 / col 128.
__device__ __forceinline__ float dpp_from_lower(float v) {
    return __int_as_float(__builtin_amdgcn_update_dpp(0, __float_as_int(v), 0x138, 0xF, 0xF, true));
}
__device__ __forceinline__ float dpp_from_upper(float v) {
    return __int_as_float(__builtin_amdgcn_update_dpp(0, __float_as_int(v), 0x130, 0xF, 0xF, true));
}

// One row update, packed-f32 friendly:
//   lap = up + dn + {lf + Y.y, Y.x + rt} - 4*Y
//   Z   = K*lap + (C2 + K2*Z)
#define ROW(up, dn, Yr, Zr, Kr) { \
    const float lf = dpp_from_lower((Yr).y); \
    const float rt = dpp_from_upper((Yr).x); \
    v2f cross; cross.x = lf + (Yr).y; cross.y = (Yr).x + rt; \
    const v2f lap = (up) + (dn) + cross - 4.0f * (Yr); \
    (Zr) = (Kr) * lap + (C2v + K2v * (Zr)); \
}

#define PR1(ownj, proj, pelj, accj, Z0,Z1,Z2,Z3,Z4,Z5,Z6,Z7) \
    if (ownj) { \
        v2f pv = Z0; \
        if (proj == 1) pv = Z1; \
        if (proj == 2) pv = Z2; \
        if (proj == 3) pv = Z3; \
        if (proj == 4) pv = Z4; \
        if (proj == 5) pv = Z5; \
        if (proj == 6) pv = Z6; \
        if (proj == 7) pv = Z7; \
        const float v = (pelj) ? pv.y : pv.x; \
        accj += v * v; \
    }

// One time step: Y* = current (read-only), Z* = previous, overwritten with new.
// Halo double-buffer selected by tt&1. Ghost row 16 is permanently zero, so
// boundary waves need no cndmask.
#define STEP(Y0,Y1,Y2,Y3,Y4,Y5,Y6,Y7, Z0,Z1,Z2,Z3,Z4,Z5,Z6,Z7, tt) { \
    const int buf_ = (tt) & 1, nb_ = buf_ ^ 1; \
    const v2f ra = *(const v2f*)&haloBot[buf_][wa][2 * l]; \
    const v2f rb = *(const v2f*)&haloTop[buf_][wb][2 * l]; \
    const float xt = xs[tt]; \
    ROW(ra, Y1, Y0, Z0, k0) \
    ROW(Y0, Y2, Y1, Z1, k1) \
    ROW(Y1, Y3, Y2, Z2, k2) \
    ROW(Y2, Y4, Y3, Z3, k3) \
    ROW(Y3, Y5, Y4, Z4, k4) \
    ROW(Y4, Y6, Y5, Z5, k5) \
    ROW(Y5, Y7, Y6, Z6, k6) \
    ROW(Y6, rb, Y7, Z7, k7) \
    if (own_src) Z0.x += xt; \
    PR1(own0, pro0, pel0, acc0, Z0,Z1,Z2,Z3,Z4,Z5,Z6,Z7) \
    PR1(own1, pro1, pel1, acc1, Z0,Z1,Z2,Z3,Z4,Z5,Z6,Z7) \
    PR1(own2, pro2, pel2, acc2, Z0,Z1,Z2,Z3,Z4,Z5,Z6,Z7) \
    PR1(own3, pro3, pel3, acc3, Z0,Z1,Z2,Z3,Z4,Z5,Z6,Z7) \
    *(v2f*)&haloTop[nb_][w][2 * l] = Z0; \
    *(v2f*)&haloBot[nb_][w][2 * l] = Z7; \
    __syncthreads(); \
}

// __launch_bounds__(1024, 4): 16-wave blocks, min 4 waves/EU = 1 block/CU.
// Grid is only 8 blocks (one per batch) so higher occupancy is unreachable;
// this lifts the VGPR cap to 128 and stops the compiler from parking the
// field state in AGPRs (round-2 kernel: VGPR_Count=36 + accvgpr shuffling).
__global__ __launch_bounds__(1024, 4) void wave_sim(
        const float* __restrict__ x,        // (T,B)
        const float* __restrict__ c,        // (NX,NY)
        const int*   __restrict__ probes,   // (4,2) int
        float* __restrict__ partial)        // (B,4)
{
    __shared__ float haloTop[2][17][NYD];   // [16] = permanent zero ghost row
    __shared__ float haloBot[2][17][NYD];
    __shared__ float xs[T_STEPSD];

    const int tid = threadIdx.x;
    const int w = tid >> 6;
    const int l = tid & 63;
    const int b = blockIdx.x;

    const float dt = 0.5f, bdamp = 0.005f;
    const float denom = 1.0f / (dt * dt) + 0.5f * bdamp / dt;  // 4.005
    const float inv_denom = 1.0f / denom;
    const float C2 = 2.0f * inv_denom;
    const float K2 = (-1.0f - dt * bdamp) * inv_denom;
    const float KL = dt * dt * inv_denom;
    v2f C2v; C2v.x = C2; C2v.y = C2;
    v2f K2v; K2v.x = K2; K2v.y = K2;

    for (int i = tid; i < 2 * 17 * NYD; i += 1024) {
        ((float*)haloTop)[i] = 0.0f;
        ((float*)haloBot)[i] = 0.0f;
    }
    if (tid < T_STEPSD) xs[tid] = x[tid * BATCHD + b];

    const int rowbase = w * 8;
    const int colb = 2 * l;
#define LOADK(r) \
    v2f k##r; { \
        const v2f cc = *(const v2f*)&c[(rowbase + r) * NYD + colb]; \
        k##r = KL * cc * cc; \
    }
    LOADK(0) LOADK(1) LOADK(2) LOADK(3) LOADK(4) LOADK(5) LOADK(6) LOADK(7)
#undef LOADK

    v2f zz; zz.x = 0.0f; zz.y = 0.0f;
    v2f a0 = zz, a1 = zz, a2 = zz, a3 = zz, a4 = zz, a5 = zz, a6 = zz, a7 = zz;
    v2f b0 = zz, b1 = zz, b2 = zz, b3 = zz, b4 = zz, b5 = zz, b6 = zz, b7 = zz;

    const int px0 = probes[0] & 127, py0 = probes[1] & 127;
    const int px1 = probes[2] & 127, py1 = probes[3] & 127;
    const int px2 = probes[4] & 127, py2 = probes[5] & 127;
    const int px3 = probes[6] & 127, py3 = probes[7] & 127;
    const bool own0 = ((px0 >> 3) == w) && ((py0 >> 1) == l);
    const bool own1 = ((px1 >> 3) == w) && ((py1 >> 1) == l);
    const bool own2 = ((px2 >> 3) == w) && ((py2 >> 1) == l);
    const bool own3 = ((px3 >> 3) == w) && ((py3 >> 1) == l);
    const int pro0 = px0 & 7, pel0 = py0 & 1;
    const int pro1 = px1 & 7, pel1 = py1 & 1;
    const int pro2 = px2 & 7, pel2 = py2 & 1;
    const int pro3 = px3 & 7, pel3 = py3 & 1;
    float acc0 = 0.f, acc1 = 0.f, acc2 = 0.f, acc3 = 0.f;
    const bool own_src = (((SRC_XD >> 3) == w) && ((SRC_YD >> 1) == l));

    const int wa = (w == 0) ? 16 : w - 1;    // 16 = zero ghost row
    const int wb = (w == 15) ? 16 : w + 1;

    __syncthreads();

#pragma unroll 1
    for (int t = 0; t < T_STEPSD; t += 2) {
        STEP(a0,a1,a2,a3,a4,a5,a6,a7, b0,b1,b2,b3,b4,b5,b6,b7, t)
        STEP(b0,b1,b2,b3,b4,b5,b6,b7, a0,a1,a2,a3,a4,a5,a6,a7, t + 1)
    }

    if (own0) partial[b * N_PROBESD + 0] = acc0;
    if (own1) partial[b * N_PROBESD + 1] = acc1;
    if (own2) partial[b * N_PROBESD + 2] = acc2;
    if (own3) partial[b * N_PROBESD + 3] = acc3;
}

__global__ void reduce_k(const float* __restrict__ partial, float* __restrict__ out) {
    const int p = threadIdx.x;
    if (p < N_PROBESD) {
        float s = 0.0f, tot = 0.0f;
        for (int bb = 0; bb < BATCHD; ++bb) s += partial[bb * N_PROBESD + p];
        for (int i = 0; i < BATCHD * N_PROBESD; ++i) tot += partial[i];
        out[p] = s / tot;
    }
}

extern "C" void kernel_launch(void* const* d_in, const int* in_sizes, int n_in,
                              void* d_out, int out_size, void* d_ws, size_t ws_size,
                              hipStream_t stream) {
    const float* x      = (const float*)d_in[0];
    const float* c      = (const float*)d_in[1];
    const int*   probes = (const int*)d_in[2];
    float* out = (float*)d_out;
    float* partial = (float*)d_ws;

    wave_sim<<<BATCHD, 1024, 0, stream>>>(x, c, probes, partial);
    reduce_k<<<1, 64, 0, stream>>>(partial, out);
}

// Round 5
// 229.621 us; speedup vs baseline: 6.5171x; 1.0257x over previous
//
#include <hip/hip_runtime.h>

#define NXD 128
#define NYD 128
#define SRC_XD 64
#define SRC_YD 64
#define T_STEPSD 256
#define BATCHD 8
#define N_PROBESD 4

typedef float v2f __attribute__((ext_vector_type(2)));

// DPP cross-lane single shifts across the full wave64.
// WAVE_SHR1 (0x138): lane i <- lane i-1, lane0 -> 0 (bound_ctrl)
// WAVE_SHL1 (0x130): lane i <- lane i+1, lane63 -> 0
// Zero-fill matches the conv 'SAME' zero padding at col -1 / col 128.
__device__ __forceinline__ float dpp_from_lower(float v) {
    return __int_as_float(__builtin_amdgcn_update_dpp(0, __float_as_int(v), 0x138, 0xF, 0xF, true));
}
__device__ __forceinline__ float dpp_from_upper(float v) {
    return __int_as_float(__builtin_amdgcn_update_dpp(0, __float_as_int(v), 0x130, 0xF, 0xF, true));
}

// One row update (2 cells), packed-f32 friendly:
//   lap = up + dn + {lf + Y.y, Y.x + rt} - 4*Y ;  Z = K*lap + (C2 + K2*Z)
#define ROW(up, dn, Yr, Zr, Kr) { \
    const float lf = dpp_from_lower((Yr).y); \
    const float rt = dpp_from_upper((Yr).x); \
    v2f cross; cross.x = lf + (Yr).y; cross.y = (Yr).x + rt; \
    const v2f lap = (up) + (dn) + cross - 4.0f * (Yr); \
    (Zr) = (Kr) * lap + (C2v + K2v * (Zr)); \
}

// Wave-uniform 16-way register select (ro is an SGPR via readfirstlane ->
// scalar branch tree, not a cndmask chain).
#define PSEL(ro, Z, pv) switch (ro) { \
    case 0:  pv = (Z##0);  break; \
    case 1:  pv = (Z##1);  break; \
    case 2:  pv = (Z##2);  break; \
    case 3:  pv = (Z##3);  break; \
    case 4:  pv = (Z##4);  break; \
    case 5:  pv = (Z##5);  break; \
    case 6:  pv = (Z##6);  break; \
    case 7:  pv = (Z##7);  break; \
    case 8:  pv = (Z##8);  break; \
    case 9:  pv = (Z##9);  break; \
    case 10: pv = (Z##10); break; \
    case 11: pv = (Z##11); break; \
    case 12: pv = (Z##12); break; \
    case 13: pv = (Z##13); break; \
    default: pv = (Z##14); break; \
    case 15: pv = (Z##15); break; \
}

// One time step: Y = current (read-only), Z = previous, overwritten with new.
// NOTE: source add hardcodes (Z##0).x -- valid because SRC_XD & 15 == 0 and
// SRC_YD is even. Probe accumulation: accv picks up garbage in non-owner
// lanes of owning waves -- harmless, only the owner lane's acc is stored.
#define STEP(Y, Z, tt) { \
    const int buf_ = (tt) & 1, nb_ = buf_ ^ 1; \
    const v2f ra = *(const v2f*)&haloBot[buf_][wa][2 * l]; \
    const v2f rb = *(const v2f*)&haloTop[buf_][wb][2 * l]; \
    ROW(ra,    Y##1,  Y##0,  Z##0,  k0) \
    ROW(Y##0,  Y##2,  Y##1,  Z##1,  k1) \
    ROW(Y##1,  Y##3,  Y##2,  Z##2,  k2) \
    ROW(Y##2,  Y##4,  Y##3,  Z##3,  k3) \
    ROW(Y##3,  Y##5,  Y##4,  Z##4,  k4) \
    ROW(Y##4,  Y##6,  Y##5,  Z##5,  k5) \
    ROW(Y##5,  Y##7,  Y##6,  Z##6,  k6) \
    ROW(Y##6,  Y##8,  Y##7,  Z##7,  k7) \
    ROW(Y##7,  Y##9,  Y##8,  Z##8,  k8) \
    ROW(Y##8,  Y##10, Y##9,  Z##9,  k9) \
    ROW(Y##9,  Y##11, Y##10, Z##10, k10) \
    ROW(Y##10, Y##12, Y##11, Z##11, k11) \
    ROW(Y##11, Y##13, Y##12, Z##12, k12) \
    ROW(Y##12, Y##14, Y##13, Z##13, k13) \
    ROW(Y##13, Y##15, Y##14, Z##14, k14) \
    ROW(Y##14, rb,    Y##15, Z##15, k15) \
    if (has_src) { if (own_src) (Z##0).x += xs[tt]; } \
    if (whas0) { v2f pv; PSEL(pro0s, Z, pv) accv0 += pv * pv; } \
    if (whas1) { v2f pv; PSEL(pro1s, Z, pv) accv1 += pv * pv; } \
    if (whas2) { v2f pv; PSEL(pro2s, Z, pv) accv2 += pv * pv; } \
    if (whas3) { v2f pv; PSEL(pro3s, Z, pv) accv3 += pv * pv; } \
    *(v2f*)&haloTop[nb_][w][2 * l] = (Z##0); \
    *(v2f*)&haloBot[nb_][w][2 * l] = (Z##15); \
    __syncthreads(); \
}

// 512 threads = 8 waves = 2 waves/EU = 1 block/CU. Unified register budget
// at 2 waves/EU is 256/wave -> the full field state (~130 regs) fits in arch
// VGPRs (at 1024 threads the 128-reg cap forced AGPR parking + accvgpr moves).
__global__ __launch_bounds__(512, 2) void wave_sim(
        const float* __restrict__ x,        // (T,B)
        const float* __restrict__ c,        // (NX,NY)
        const int*   __restrict__ probes,   // (4,2) int
        float* __restrict__ partial)        // (B,4)
{
    __shared__ float haloTop[2][9][NYD];    // [8] = permanent zero ghost row
    __shared__ float haloBot[2][9][NYD];
    __shared__ float xs[T_STEPSD];

    const int tid = threadIdx.x;
    const int w = tid >> 6;       // wave 0..7, owns rows 16w..16w+15
    const int l = tid & 63;       // lane, owns cols 2l, 2l+1
    const int b = blockIdx.x;

    const float dt = 0.5f, bdamp = 0.005f;
    const float denom = 1.0f / (dt * dt) + 0.5f * bdamp / dt;  // 4.005
    const float inv_denom = 1.0f / denom;
    const float C2 = 2.0f * inv_denom;
    const float K2 = (-1.0f - dt * bdamp) * inv_denom;
    const float KL = dt * dt * inv_denom;
    v2f C2v; C2v.x = C2; C2v.y = C2;
    v2f K2v; K2v.x = K2; K2v.y = K2;

    for (int i = tid; i < 2 * 9 * NYD; i += 512) {
        ((float*)haloTop)[i] = 0.0f;
        ((float*)haloBot)[i] = 0.0f;
    }
    if (tid < T_STEPSD) xs[tid] = x[tid * BATCHD + b];

    const int rowbase = w * 16;
    const int colb = 2 * l;
#define LOADK(r) \
    v2f k##r; { \
        const v2f cc = *(const v2f*)&c[(rowbase + r) * NYD + colb]; \
        k##r = KL * cc * cc; \
    }
    LOADK(0) LOADK(1) LOADK(2) LOADK(3) LOADK(4) LOADK(5) LOADK(6) LOADK(7)
    LOADK(8) LOADK(9) LOADK(10) LOADK(11) LOADK(12) LOADK(13) LOADK(14) LOADK(15)
#undef LOADK

    v2f zz; zz.x = 0.0f; zz.y = 0.0f;
    v2f a0 = zz, a1 = zz, a2 = zz, a3 = zz, a4 = zz, a5 = zz, a6 = zz, a7 = zz,
        a8 = zz, a9 = zz, a10 = zz, a11 = zz, a12 = zz, a13 = zz, a14 = zz, a15 = zz;
    v2f b0 = zz, b1 = zz, b2 = zz, b3 = zz, b4 = zz, b5 = zz, b6 = zz, b7 = zz,
        b8 = zz, b9 = zz, b10 = zz, b11 = zz, b12 = zz, b13 = zz, b14 = zz, b15 = zz;

    // probes: coordinates are wave-uniform (same global load in every lane)
    const int px0 = probes[0] & 127, py0 = probes[1] & 127;
    const int px1 = probes[2] & 127, py1 = probes[3] & 127;
    const int px2 = probes[4] & 127, py2 = probes[5] & 127;
    const int px3 = probes[6] & 127, py3 = probes[7] & 127;
    const bool own0 = ((px0 >> 4) == w) && ((py0 >> 1) == l);
    const bool own1 = ((px1 >> 4) == w) && ((py1 >> 1) == l);
    const bool own2 = ((px2 >> 4) == w) && ((py2 >> 1) == l);
    const bool own3 = ((px3 >> 4) == w) && ((py3 >> 1) == l);
    const bool whas0 = __ballot(own0) != 0ULL;   // uniform: does THIS wave hold probe 0
    const bool whas1 = __ballot(own1) != 0ULL;
    const bool whas2 = __ballot(own2) != 0ULL;
    const bool whas3 = __ballot(own3) != 0ULL;
    const int pro0s = __builtin_amdgcn_readfirstlane(px0 & 15);
    const int pro1s = __builtin_amdgcn_readfirstlane(px1 & 15);
    const int pro2s = __builtin_amdgcn_readfirstlane(px2 & 15);
    const int pro3s = __builtin_amdgcn_readfirstlane(px3 & 15);
    const int pel0 = py0 & 1, pel1 = py1 & 1, pel2 = py2 & 1, pel3 = py3 & 1;
    v2f accv0 = zz, accv1 = zz, accv2 = zz, accv3 = zz;

    const bool has_src = (w == (SRC_XD >> 4));            // uniform
    const bool own_src = has_src && (l == (SRC_YD >> 1)); // SRC_YD even -> .x

    const int wa = (w == 0) ? 8 : w - 1;    // 8 = zero ghost row
    const int wb = (w == 7) ? 8 : w + 1;

    __syncthreads();

#pragma unroll 1
    for (int t = 0; t < T_STEPSD; t += 2) {
        STEP(a, b, t)
        STEP(b, a, t + 1)
    }

    if (own0) partial[b * N_PROBESD + 0] = pel0 ? accv0.y : accv0.x;
    if (own1) partial[b * N_PROBESD + 1] = pel1 ? accv1.y : accv1.x;
    if (own2) partial[b * N_PROBESD + 2] = pel2 ? accv2.y : accv2.x;
    if (own3) partial[b * N_PROBESD + 3] = pel3 ? accv3.y : accv3.x;
}

__global__ void reduce_k(const float* __restrict__ partial, float* __restrict__ out) {
    const int p = threadIdx.x;
    if (p < N_PROBESD) {
        float s = 0.0f, tot = 0.0f;
        for (int bb = 0; bb < BATCHD; ++bb) s += partial[bb * N_PROBESD + p];
        for (int i = 0; i < BATCHD * N_PROBESD; ++i) tot += partial[i];
        out[p] = s / tot;
    }
}

extern "C" void kernel_launch(void* const* d_in, const int* in_sizes, int n_in,
                              void* d_out, int out_size, void* d_ws, size_t ws_size,
                              hipStream_t stream) {
    const float* x      = (const float*)d_in[0];
    const float* c      = (const float*)d_in[1];
    const int*   probes = (const int*)d_in[2];
    float* out = (float*)d_out;
    float* partial = (float*)d_ws;

    wave_sim<<<BATCHD, 512, 0, stream>>>(x, c, probes, partial);
    reduce_k<<<1, 64, 0, stream>>>(partial, out);
}